// Round 11
// baseline (38.543 us; speedup 1.0000x reference)
//
#include <hip/hip_runtime.h>
#include <math.h>

// Problem constants
#define BB 512
#define VV 2
#define MM 1024
#define DD 128
#define KMAX 50
#define TOPK 15
#define INV_T (1.0f/0.07f)

// ---------------- Workspace layout (byte offsets) ----------------
#define OFF_ANCH  0                      // bf16 [MM][DD]   256 KB
#define OFF_A2    262144                 // f32  [MM]         4 KB
#define OFF_ACCT  266240                 // f32  [BB][MM]     2 MB : accT[b][i] = acc(i,b)
#define OFF_PART  (266240 + 2097152)     // f32  [16][MM]    64 KB : per-jg partial expsums
#define OFF_LSPOS (OFF_PART + 65536)     // f32  [MM]         4 KB

typedef __attribute__((ext_vector_type(8))) short bf16x8;
typedef __attribute__((ext_vector_type(4))) float f32x4;

// f32 -> bf16 (RNE)
__device__ __forceinline__ short f2bf(float x)
{
    union { float f; unsigned u; } a; a.f = x;
    return (short)((a.u + 0x7FFFu + ((a.u >> 16) & 1u)) >> 16);
}

// convert 8 f32 (two float4) to bf16x8, accumulating sum of squares
__device__ __forceinline__ bf16x8 cvt8(float4 p0, float4 p1, float& nacc)
{
    float v[8] = {p0.x, p0.y, p0.z, p0.w, p1.x, p1.y, p1.z, p1.w};
    bf16x8 r;
    #pragma unroll
    for (int e = 0; e < 8; ++e) {
        nacc = fmaf(v[e], v[e], nacc);
        r[e] = f2bf(v[e]);
    }
    return r;
}

// ---------------------------------------------------------------------------
// K0: anchor (transposed features) -> bf16 + exact f32 norms.  (R6 verbatim)
// 256 blocks x 256 thr; wave per row.
// ---------------------------------------------------------------------------
__global__ __launch_bounds__(256) void k0_anchor(
    const float* __restrict__ feat,
    unsigned* __restrict__ anchor_u,     // bf16 pairs packed as u32
    float* __restrict__ a2)
{
    const int row  = blockIdx.x * 4 + (threadIdx.x >> 6);
    const int lane = threadIdx.x & 63;
    const int frow = (row & (BB - 1)) * VV + (row >> 9);
    float2 v = *(const float2*)&feat[(size_t)frow * DD + lane * 2];
    unsigned lo = (unsigned)(unsigned short)f2bf(v.x);
    unsigned hi = (unsigned)(unsigned short)f2bf(v.y);
    anchor_u[row * (DD / 2) + lane] = lo | (hi << 16);
    float sq = v.x * v.x + v.y * v.y;
    #pragma unroll
    for (int off = 32; off > 0; off >>= 1) sq += __shfl_xor(sq, off);
    if (lane == 0) a2[row] = sq;
}

// ---------------------------------------------------------------------------
// K1: neighbor MFMA GEMM -> accT[b][i].
// Grid (128, 8): block = 64 neighbor rows x 128 anchor cols (NO inner j-loop)
// -> 1024 blocks / 4096 waves for cold-latency hiding (R8: Occ was 11%).
// A side gathered from saved (f32->bf16 in-register + exact shfl norms);
// B side reads K0's staged bf16 anchor.
// C layout (mfma_f32_16x16x32_bf16): col = lane&15, row(k) = (lane>>4)*4 + reg.
// ---------------------------------------------------------------------------
__global__ __launch_bounds__(256) void k1_acc(
    const short* __restrict__ anchor,    // bf16 [MM][DD]
    const float* __restrict__ a2,
    const int* __restrict__ indices,
    const float* __restrict__ saved, const int* __restrict__ rks,
    float* __restrict__ accT)
{
    const int tid = threadIdx.x;
    const int lane = tid & 63;
    const int wid = tid >> 6;
    const int lr = lane & 15;
    const int lg = lane >> 4;
    const int wr = wid >> 1;
    const int wc = wid & 1;
    const int m0 = blockIdx.x * 64 + wr * 32;        // neighbor row base
    const int j0 = blockIdx.y * 128 + wc * 64;       // anchor col base

    // A side: gather 2 b-groups' saved rows (k = lr; k=15 masked in epilogue)
    int aidx[2];
    #pragma unroll
    for (int tm = 0; tm < 2; ++tm) {
        int b = (m0 >> 4) + tm;
        aidx[tm] = rks[(size_t)indices[b] * KMAX + lr];
    }
    bf16x8 af[2][4];
    float nnA[2] = {0.f, 0.f};
    #pragma unroll
    for (int tm = 0; tm < 2; ++tm)
        #pragma unroll
        for (int kc = 0; kc < 4; ++kc) {
            const float4* p = (const float4*)&saved[(size_t)aidx[tm] * DD + kc * 32 + lg * 8];
            af[tm][kc] = cvt8(p[0], p[1], nnA[tm]);
        }
    #pragma unroll
    for (int tm = 0; tm < 2; ++tm) {
        nnA[tm] += __shfl_xor(nnA[tm], 16);
        nnA[tm] += __shfl_xor(nnA[tm], 32);          // lane: full norm of row lr
    }
    float nnAr[2][4];
    #pragma unroll
    for (int tm = 0; tm < 2; ++tm)
        #pragma unroll
        for (int r = 0; r < 4; ++r)
            nnAr[tm][r] = __shfl(nnA[tm], lg * 4 + r);   // norm of C-row lg*4+r

    // B side: staged bf16 anchor, MFMA accumulate
    f32x4 acc[2][4];
    #pragma unroll
    for (int a = 0; a < 2; ++a)
        #pragma unroll
        for (int b = 0; b < 4; ++b) acc[a][b] = (f32x4){0.f, 0.f, 0.f, 0.f};
    #pragma unroll
    for (int kc = 0; kc < 4; ++kc) {
        bf16x8 bf[4];
        #pragma unroll
        for (int tn = 0; tn < 4; ++tn)
            bf[tn] = *(const bf16x8*)&anchor[(size_t)(j0 + tn * 16 + lr) * DD + kc * 32 + lg * 8];
        #pragma unroll
        for (int tm = 0; tm < 2; ++tm)
            #pragma unroll
            for (int tn = 0; tn < 4; ++tn)
                acc[tm][tn] = __builtin_amdgcn_mfma_f32_16x16x32_bf16(
                    af[tm][kc], bf[tn], acc[tm][tn], 0, 0, 0);
    }

    // epilogue: f(dist), mask pad row, reduce 16 k-rows, store accT
    #pragma unroll
    for (int tm = 0; tm < 2; ++tm) {
        const int b = (m0 >> 4) + tm;
        #pragma unroll
        for (int tn = 0; tn < 4; ++tn) {
            const float a2j = a2[j0 + tn * 16 + lr];
            float s = 0.f;
            #pragma unroll
            for (int r = 0; r < 4; ++r) {
                float g = acc[tm][tn][r];
                float sq = fmaxf(fmaf(-2.f, g, a2j + nnAr[tm][r]), 0.f);
                float d = __builtin_amdgcn_sqrtf(sq);
                float f = fmaf(__builtin_amdgcn_rcpf(1.f + d), INV_T, INV_T);
                if (lg == 3 && r == 3) f = 0.f;      // k == 15 pad row
                s += f;
            }
            s += __shfl_xor(s, 16);
            s += __shfl_xor(s, 32);                  // sum the 16 k-rows
            if (lane < 16)
                accT[(size_t)b * MM + j0 + tn * 16 + lane] = s * (1.0f / TOPK);
        }
    }
}

// ---------------------------------------------------------------------------
// K2: S-tile MFMA + adc + ls + exp partial sums.  (R6 verbatim)
// Grid (64, 16): 16 i-rows x 64 j-cols per block; wave handles 16 cols.
// (No max subtraction: ls in [24.7, 49.5]; verified rounds 4-10, absmax 0.)
// ---------------------------------------------------------------------------
__global__ __launch_bounds__(256) void k2_exp(
    const short* __restrict__ anchor, const float* __restrict__ a2,
    const float* __restrict__ accT,
    float* __restrict__ part, float* __restrict__ lspos)
{
    __shared__ float pshare[4][16];
    const int tid = threadIdx.x;
    const int lane = tid & 63;
    const int wid = tid >> 6;
    const int lr = lane & 15;
    const int lg = lane >> 4;
    const int i0 = blockIdx.x * 16;
    const int jg = blockIdx.y;
    const int jcol = jg * 64 + wid * 16 + lr;

    f32x4 acc = (f32x4){0.f, 0.f, 0.f, 0.f};
    #pragma unroll
    for (int kc = 0; kc < 4; ++kc) {
        bf16x8 af = *(const bf16x8*)&anchor[(size_t)(i0 + lr) * DD + kc * 32 + lg * 8];
        bf16x8 bf = *(const bf16x8*)&anchor[(size_t)jcol * DD + kc * 32 + lg * 8];
        acc = __builtin_amdgcn_mfma_f32_16x16x32_bf16(af, bf, acc, 0, 0, 0);
    }
    const int ib4 = i0 + lg * 4;
    const float4 a2i4 = *(const float4*)&a2[ib4];
    const float a2iv[4] = {a2i4.x, a2i4.y, a2i4.z, a2i4.w};
    const float a2j = a2[jcol];
    const float4 aij4 = *(const float4*)&accT[(size_t)(jcol & (BB - 1)) * MM + ib4];
    const float aijv[4] = {aij4.x, aij4.y, aij4.z, aij4.w};

    float esum[4];
    #pragma unroll
    for (int r = 0; r < 4; ++r) {
        const int i = ib4 + r;
        float g = acc[r];
        float sq = fmaxf(fmaf(-2.f, g, a2iv[r] + a2j), 0.f);
        float d0 = __builtin_amdgcn_sqrtf(sq);
        float adc = fmaf(__builtin_amdgcn_rcpf(1.f + d0), INV_T, INV_T);
        float aji = accT[(size_t)(i & (BB - 1)) * MM + jcol];
        float ls = __builtin_amdgcn_sqrtf(aijv[r] * aijv[r] + aji * aji + adc * adc);
        esum[r] = (jcol == i) ? 0.f : __expf(ls);
        if (jcol == (i ^ BB)) lspos[i] = ls;            // the positive pair
    }
    #pragma unroll
    for (int r = 0; r < 4; ++r) {
        float e = esum[r];
        e += __shfl_xor(e, 1);
        e += __shfl_xor(e, 2);
        e += __shfl_xor(e, 4);
        e += __shfl_xor(e, 8);                          // sum 16 j's in wave
        if (lr == 0) pshare[wid][lg * 4 + r] = e;
    }
    __syncthreads();
    if (tid < 16)
        part[jg * MM + i0 + tid] =
            pshare[0][tid] + pshare[1][tid] + pshare[2][tid] + pshare[3][tid];
}

// ---------------------------------------------------------------------------
// K3: finish — loss per row + mean, single block.  (R6 verbatim)
// ---------------------------------------------------------------------------
__global__ __launch_bounds__(256) void k3_finish(
    const float* __restrict__ part, const float* __restrict__ lspos,
    float* __restrict__ out)
{
    __shared__ float red[4];
    const int tid = threadIdx.x;
    const int lane = tid & 63, w = tid >> 6;
    float lsum = 0.f;
    #pragma unroll
    for (int q = 0; q < 4; ++q) {
        const int i = tid + q * 256;
        float s = 0.f;
        #pragma unroll
        for (int jg = 0; jg < 16; ++jg) s += part[jg * MM + i];
        lsum += __logf(s) - lspos[i];
    }
    #pragma unroll
    for (int off = 32; off > 0; off >>= 1) lsum += __shfl_xor(lsum, off);
    if (lane == 0) red[w] = lsum;
    __syncthreads();
    if (tid == 0) out[0] = (red[0] + red[1] + red[2] + red[3]) * (1.0f / MM);
}

// ---------------------------------------------------------------------------
extern "C" void kernel_launch(void* const* d_in, const int* in_sizes, int n_in,
                              void* d_out, int out_size, void* d_ws, size_t ws_size,
                              hipStream_t stream)
{
    const float* feat    = (const float*)d_in[0];  // (512, 2, 128) f32
    const int*   indices = (const int*)  d_in[1];  // (512,) i32
    const float* saved   = (const float*)d_in[2];  // (100000, 128) f32
    const int*   rks     = (const int*)  d_in[3];  // (100000, 50) i32

    char* w = (char*)d_ws;
    short* anchor = (short*)(w + OFF_ANCH);
    float* a2     = (float*)(w + OFF_A2);
    float* accT   = (float*)(w + OFF_ACCT);
    float* part   = (float*)(w + OFF_PART);
    float* lspos  = (float*)(w + OFF_LSPOS);

    // K0: anchor -> bf16 + exact norms
    k0_anchor<<<MM / 4, 256, 0, stream>>>(feat, (unsigned*)anchor, a2);
    // K1: neighbor GEMM -> accT  (grid (128,8): 2x occupancy vs R6)
    k1_acc<<<dim3(128, 8), 256, 0, stream>>>(anchor, a2, indices, saved, rks, accT);
    // K2: S-GEMM + adc + exp partials -> part, lspos
    k2_exp<<<dim3(64, 16), 256, 0, stream>>>(anchor, a2, accT, part, lspos);
    // K3: loss + mean
    k3_finish<<<1, 256, 0, stream>>>(part, lspos, (float*)d_out);
}